// Round 4
// baseline (111.109 us; speedup 1.0000x reference)
//
#include <hip/hip_runtime.h>
#include <hip/hip_bf16.h>

#define NTHREADS 512

typedef __attribute__((ext_vector_type(8))) short short8;
typedef __attribute__((ext_vector_type(4))) float f32x4;

#define MFMA(a, b, c) __builtin_amdgcn_mfma_f32_16x16x32_bf16(a, b, c, 0, 0, 0)

__device__ __forceinline__ unsigned short f2u(float x) {
    __hip_bfloat16 b = __float2bfloat16(x);
    return *reinterpret_cast<unsigned short*>(&b);
}
__device__ __forceinline__ float u2f(unsigned short u) {
    unsigned v = ((unsigned)u) << 16;
    return *reinterpret_cast<float*>(&v);
}
__device__ __forceinline__ unsigned pack2(float lo, float hi) {
    return ((unsigned)f2u(hi) << 16) | (unsigned)f2u(lo);
}
// XOR-swizzled byte offsets. [R][64] bf16 rows (128B, 8 chunks of 16B):
__device__ __forceinline__ int swz64(int r, int c8)  { return r * 128 + ((c8 ^ (r & 7)) << 4); }
__device__ __forceinline__ int swz64e(int r, int c)  { return r * 128 + (((c >> 3) ^ (r & 7)) << 4) + ((c & 7) << 1); }
// [R][256B] rows (16 chunks of 16B) — used for bf16 [R][128] and fp32 [R][64]:
__device__ __forceinline__ int swz128(int r, int c8) { return r * 256 + ((c8 ^ (r & 15)) << 4); }
__device__ __forceinline__ int swz128e(int r, int c) { return r * 256 + ((((c >> 3) ^ (r & 15))) << 4) + ((c & 7) << 1); }

__device__ __forceinline__ short8 cvt8(const float* src) {
    float4 f0 = *(const float4*)src;
    float4 f1 = *(const float4*)(src + 4);
    short8 v = { (short)f2u(f0.x), (short)f2u(f0.y), (short)f2u(f0.z), (short)f2u(f0.w),
                 (short)f2u(f1.x), (short)f2u(f1.y), (short)f2u(f1.z), (short)f2u(f1.w) };
    return v;
}

// repack D-layout (row=4g'+jr within K-tile, col=l15) values into a B-fragment
// for the K=32 MFMA chunk kc. p0..p3 are pack2 words of tiles 2kc (p0,p1) and 2kc+1 (p2,p3).
__device__ __forceinline__ short8 repack4(unsigned p0, unsigned p1, unsigned p2, unsigned p3,
                                          int src0, int src1, bool hiMt) {
    unsigned a0 = __shfl((int)p0, src0), a1 = __shfl((int)p1, src0);
    unsigned b0 = __shfl((int)p2, src0), b1 = __shfl((int)p3, src0);
    unsigned a2 = __shfl((int)p0, src1), a3 = __shfl((int)p1, src1);
    unsigned b2 = __shfl((int)p2, src1), b3 = __shfl((int)p3, src1);
    union { unsigned u[4]; short8 s8; } pf;
    pf.u[0] = hiMt ? b0 : a0;
    pf.u[1] = hiMt ? b1 : a1;
    pf.u[2] = hiMt ? b2 : a2;
    pf.u[3] = hiMt ? b3 : a3;
    return pf.s8;
}

__global__ __launch_bounds__(NTHREADS, 6) void gal_kernel(
    const float* __restrict__ h,  const float* __restrict__ W,
    const float* __restrict__ wq, const float* __restrict__ bq,
    const float* __restrict__ wk, const float* __restrict__ bk,
    const float* __restrict__ wv, const float* __restrict__ bv,
    const float* __restrict__ wo, const float* __restrict__ bo,
    const float* __restrict__ we, const float* __restrict__ be,
    const float* __restrict__ g1, const float* __restrict__ b1,
    const float* __restrict__ w1, const float* __restrict__ bf1,
    const float* __restrict__ w2, const float* __restrict__ bff2,
    const float* __restrict__ g2, const float* __restrict__ b2,
    float* __restrict__ out)
{
    // 48 KB LDS, phase-overlaid:
    // A: s_h@0[128][64], wq@16K, wk@24K, wv@32K (each [64][64] 8K)
    // B: s_Q@0[128][64], s_K@16K[128][64], s_VT@32K[64][128]
    // C/D: w2@0[64][128], wo@16K[64][64], w1@24K[128][64]
    // end: s_y fp32 [128][64] @16K..48K (swz128)
    __shared__ __align__(16) unsigned char smem[49152];

    const int gblk = blockIdx.x;
    const int b   = gblk >> 7;
    const int tt  = gblk & 127;
    const int tid = threadIdx.x;
    const int lane = tid & 63;
    const int w   = tid >> 6;      // wave 0..7 owns q-rows 16w..16w+15
    const int l15 = lane & 15;
    const int g   = lane >> 4;     // quarter-group 0..3

    const float* hp = h + (((size_t)b * 128) * 128 + tt) * 64;
    const float* Wb = W + (size_t)b * 128 * 128;

    // ================= Phase A: stage h + QKV weights =================
#pragma unroll
    for (int i = 0; i < 2; ++i) {
        int idx = tid + i * 512;
        int d = idx >> 3, c = idx & 7;
        *(short8*)(smem + swz64(d, c)) = cvt8(hp + (size_t)d * 8192 + c * 8);
    }
    {
        int j = tid >> 3, c = tid & 7;   // 512 threads cover 64x8 exactly
        *(short8*)(smem + 16384 + swz64(j, c)) = cvt8(wq + j * 64 + c * 8);
        *(short8*)(smem + 24576 + swz64(j, c)) = cvt8(wk + j * 64 + c * 8);
        *(short8*)(smem + 32768 + swz64(j, c)) = cvt8(wv + j * 64 + c * 8);
    }
    __syncthreads();   // (1)

    // QKV GEMMs into registers: wave w owns rows 16w..16w+15
    f32x4 aq[4], ak4[4], av4[4];
    {
        short8 ah0 = *(const short8*)(smem + swz64(16 * w + l15, g));
        short8 ah1 = *(const short8*)(smem + swz64(16 * w + l15, g + 4));
        f32x4 z = {0.f, 0.f, 0.f, 0.f};
#pragma unroll
        for (int nt = 0; nt < 4; ++nt) { aq[nt] = z; ak4[nt] = z; av4[nt] = z; }
#pragma unroll
        for (int nt = 0; nt < 4; ++nt) {
#pragma unroll
            for (int kh = 0; kh < 2; ++kh) {
                short8 ah = kh ? ah1 : ah0;
                short8 bwq = *(const short8*)(smem + 16384 + swz64(16 * nt + l15, g + 4 * kh));
                aq[nt] = MFMA(ah, bwq, aq[nt]);
                short8 bwk = *(const short8*)(smem + 24576 + swz64(16 * nt + l15, g + 4 * kh));
                ak4[nt] = MFMA(ah, bwk, ak4[nt]);
                short8 bwv = *(const short8*)(smem + 32768 + swz64(16 * nt + l15, g + 4 * kh));
                av4[nt] = MFMA(ah, bwv, av4[nt]);
            }
        }
    }
    float bqv[4], bkv[4], bvv[4];
#pragma unroll
    for (int nt = 0; nt < 4; ++nt) {
        bqv[nt] = bq[16 * nt + l15]; bkv[nt] = bk[16 * nt + l15]; bvv[nt] = bv[16 * nt + l15];
    }
    __syncthreads();   // (2) all LDS reads done before overwrite
    // write s_Q@0 (row d), s_K@16K (row d), s_VT@32K (row j = H-dim)
#pragma unroll
    for (int nt = 0; nt < 4; ++nt) {
        int j = 16 * nt + l15;
#pragma unroll
        for (int jr = 0; jr < 4; ++jr) {
            int d = 16 * w + 4 * g + jr;
            *(unsigned short*)(smem + swz64e(d, j))          = f2u((aq[nt][jr] + bqv[nt]) * 0.25f);
            *(unsigned short*)(smem + 16384 + swz64e(d, j))  = f2u(ak4[nt][jr] + bkv[nt]);
            *(unsigned short*)(smem + 32768 + swz128e(j, d)) = f2u(av4[nt][jr] + bvv[nt]);
        }
    }
    __syncthreads();   // (3)

    // ================= Phase B: attention (swapped S^T = K*Q^T) =================
    const int q = 16 * w + l15;                 // this lane's q-row
    const int src0 = l15 + ((lane & 16) << 1);  // quarter-shuffle sources
    const int src1 = src0 + 16;
    const bool hiMt = (g >> 1) & 1;

    float osr[4][4];   // O^T[16hd+4g+jr][q] accumulated per head
#pragma unroll
    for (int hd = 0; hd < 4; ++hd) {
        float weh = we[hd];                     // be cancels in softmax
        short8 qf = {0, 0, 0, 0, 0, 0, 0, 0};
        if (g < 2) qf = *(const short8*)(smem + swz64(q, 2 * hd + g));
        f32x4 s[8];
#pragma unroll
        for (int Mt = 0; Mt < 8; ++Mt) {
            float4 w4 = *(const float4*)(Wb + (size_t)q * 128 + 16 * Mt + 4 * g);
            f32x4 c0 = { w4.x * weh, w4.y * weh, w4.z * weh, w4.w * weh };
            short8 kf = {0, 0, 0, 0, 0, 0, 0, 0};
            if (g < 2) kf = *(const short8*)(smem + 16384 + swz64(16 * Mt + l15, 2 * hd + g));
            s[Mt] = MFMA(kf, qf, c0);
        }
        // softmax over kk (row q lives in 4 lanes x 32 regs)
        float mx = s[0][0];
#pragma unroll
        for (int Mt = 0; Mt < 8; ++Mt)
#pragma unroll
            for (int jr = 0; jr < 4; ++jr) mx = fmaxf(mx, s[Mt][jr]);
        mx = fmaxf(mx, __shfl_xor(mx, 16));
        mx = fmaxf(mx, __shfl_xor(mx, 32));
        float tot = 0.f;
#pragma unroll
        for (int Mt = 0; Mt < 8; ++Mt)
#pragma unroll
            for (int jr = 0; jr < 4; ++jr) { s[Mt][jr] = __expf(s[Mt][jr] - mx); tot += s[Mt][jr]; }
        tot += __shfl_xor(tot, 16);
        tot += __shfl_xor(tot, 32);
        float sinv = 1.f / tot;
        unsigned pk[16];
#pragma unroll
        for (int Mt = 0; Mt < 8; ++Mt) {
            pk[2 * Mt]     = pack2(s[Mt][0], s[Mt][1]);
            pk[2 * Mt + 1] = pack2(s[Mt][2], s[Mt][3]);
        }
        // PV: O^T = V^T @ P^T
        f32x4 o = {0.f, 0.f, 0.f, 0.f};
#pragma unroll
        for (int kc = 0; kc < 4; ++kc) {
            short8 pf = repack4(pk[4 * kc], pk[4 * kc + 1], pk[4 * kc + 2], pk[4 * kc + 3],
                                src0, src1, hiMt);
            short8 vf = *(const short8*)(smem + 32768 + swz128(16 * hd + l15, g + 4 * kc));
            o = MFMA(vf, pf, o);
        }
#pragma unroll
        for (int jr = 0; jr < 4; ++jr) osr[hd][jr] = o[jr] * sinv;
    }

    // h^T residual prefetch (global fp32, issued before the barrier)
    float4 hres[4];
#pragma unroll
    for (int Mt2 = 0; Mt2 < 4; ++Mt2)
        hres[Mt2] = *(const float4*)(hp + (size_t)q * 8192 + 16 * Mt2 + 4 * g);
    __syncthreads();   // (4) attention LDS reads done

    // stage w2@0 [64][128], wo@16K [64][64], w1@24K [128][64]
    {
        int j = tid >> 3, c = tid & 7;
        *(short8*)(smem + 16384 + swz64(j, c)) = cvt8(wo + j * 64 + c * 8);
    }
#pragma unroll
    for (int i = 0; i < 2; ++i) {
        int idx = tid + i * 512;
        int m = idx >> 3, c = idx & 7;
        *(short8*)(smem + 24576 + swz64(m, c)) = cvt8(w1 + m * 64 + c * 8);
        int j2 = idx >> 4, c2 = idx & 15;
        *(short8*)(smem + swz128(j2, c2)) = cvt8(w2 + j2 * 128 + c2 * 8);
    }
    __syncthreads();   // (5)

    // ============ Phase C: out-proj (transposed) + residual + LN1, all in regs ============
    f32x4 xt[4];
#pragma unroll
    for (int Mt2 = 0; Mt2 < 4; ++Mt2) {
        float4 bb = *(const float4*)(bo + 16 * Mt2 + 4 * g);
        f32x4 c0 = { bb.x, bb.y, bb.z, bb.w };
        xt[Mt2] = c0;
    }
#pragma unroll
    for (int kc = 0; kc < 2; ++kc) {
        short8 pf = repack4(pack2(osr[2 * kc][0], osr[2 * kc][1]),
                            pack2(osr[2 * kc][2], osr[2 * kc][3]),
                            pack2(osr[2 * kc + 1][0], osr[2 * kc + 1][1]),
                            pack2(osr[2 * kc + 1][2], osr[2 * kc + 1][3]),
                            src0, src1, hiMt);
#pragma unroll
        for (int Mt2 = 0; Mt2 < 4; ++Mt2) {
            short8 awo = *(const short8*)(smem + 16384 + swz64(16 * Mt2 + l15, g + 4 * kc));
            xt[Mt2] = MFMA(awo, pf, xt[Mt2]);
        }
    }
    // residual + LN1 over H-dim (in-lane 16 + shfl 16/32)
    {
        float ps = 0.f, pq = 0.f;
#pragma unroll
        for (int Mt2 = 0; Mt2 < 4; ++Mt2) {
            float4 hv = hres[Mt2];
            xt[Mt2][0] += hv.x; xt[Mt2][1] += hv.y; xt[Mt2][2] += hv.z; xt[Mt2][3] += hv.w;
#pragma unroll
            for (int jr = 0; jr < 4; ++jr) { ps += xt[Mt2][jr]; pq += xt[Mt2][jr] * xt[Mt2][jr]; }
        }
        ps += __shfl_xor(ps, 16); ps += __shfl_xor(ps, 32);
        pq += __shfl_xor(pq, 16); pq += __shfl_xor(pq, 32);
        float mu = ps * (1.f / 64.f);
        float va = pq * (1.f / 64.f) - mu * mu;
        float is = rsqrtf(va + 1e-5f);
#pragma unroll
        for (int Mt2 = 0; Mt2 < 4; ++Mt2) {
            float4 g4 = *(const float4*)(g1 + 16 * Mt2 + 4 * g);
            float4 b4 = *(const float4*)(b1 + 16 * Mt2 + 4 * g);
            xt[Mt2][0] = (xt[Mt2][0] - mu) * is * g4.x + b4.x;
            xt[Mt2][1] = (xt[Mt2][1] - mu) * is * g4.y + b4.y;
            xt[Mt2][2] = (xt[Mt2][2] - mu) * is * g4.z + b4.z;
            xt[Mt2][3] = (xt[Mt2][3] - mu) * is * g4.w + b4.w;
        }
    }

    // ============ Phase D: FFN (transposed) + residual + LN2 ============
    f32x4 tacc[8];
#pragma unroll
    for (int Mt = 0; Mt < 8; ++Mt) {
        float4 bb = *(const float4*)(bf1 + 16 * Mt + 4 * g);
        f32x4 c0 = { bb.x, bb.y, bb.z, bb.w };
        tacc[Mt] = c0;
    }
#pragma unroll
    for (int kc = 0; kc < 2; ++kc) {
        short8 pf = repack4(pack2(xt[2 * kc][0], xt[2 * kc][1]),
                            pack2(xt[2 * kc][2], xt[2 * kc][3]),
                            pack2(xt[2 * kc + 1][0], xt[2 * kc + 1][1]),
                            pack2(xt[2 * kc + 1][2], xt[2 * kc + 1][3]),
                            src0, src1, hiMt);
#pragma unroll
        for (int Mt = 0; Mt < 8; ++Mt) {
            short8 aw1 = *(const short8*)(smem + 24576 + swz64(16 * Mt + l15, g + 4 * kc));
            tacc[Mt] = MFMA(aw1, pf, tacc[Mt]);
        }
    }
    unsigned pkt[16];
#pragma unroll
    for (int Mt = 0; Mt < 8; ++Mt) {
        float v0 = tacc[Mt][0], v1 = tacc[Mt][1], v2 = tacc[Mt][2], v3 = tacc[Mt][3];
        v0 = 0.5f * v0 * (1.f + erff(v0 * 0.70710678118f));
        v1 = 0.5f * v1 * (1.f + erff(v1 * 0.70710678118f));
        v2 = 0.5f * v2 * (1.f + erff(v2 * 0.70710678118f));
        v3 = 0.5f * v3 * (1.f + erff(v3 * 0.70710678118f));
        pkt[2 * Mt]     = pack2(v0, v1);
        pkt[2 * Mt + 1] = pack2(v2, v3);
    }
    __syncthreads();   // (6) w1/wo reads done; s_y may overwrite them after this

    f32x4 ya[4];
#pragma unroll
    for (int Mt2 = 0; Mt2 < 4; ++Mt2) {
        float4 bb = *(const float4*)(bff2 + 16 * Mt2 + 4 * g);
        f32x4 c0 = { bb.x, bb.y, bb.z, bb.w };
        ya[Mt2] = c0;
    }
#pragma unroll
    for (int kc = 0; kc < 4; ++kc) {
        short8 pf = repack4(pkt[4 * kc], pkt[4 * kc + 1], pkt[4 * kc + 2], pkt[4 * kc + 3],
                            src0, src1, hiMt);
#pragma unroll
        for (int Mt2 = 0; Mt2 < 4; ++Mt2) {
            short8 aw2 = *(const short8*)(smem + swz128(16 * Mt2 + l15, g + 4 * kc));
            ya[Mt2] = MFMA(aw2, pf, ya[Mt2]);
        }
    }
    // residual from xt (in regs) + LN2
    {
        float ps = 0.f, pq = 0.f;
#pragma unroll
        for (int Mt2 = 0; Mt2 < 4; ++Mt2) {
#pragma unroll
            for (int jr = 0; jr < 4; ++jr) {
                ya[Mt2][jr] += xt[Mt2][jr];
                ps += ya[Mt2][jr]; pq += ya[Mt2][jr] * ya[Mt2][jr];
            }
        }
        ps += __shfl_xor(ps, 16); ps += __shfl_xor(ps, 32);
        pq += __shfl_xor(pq, 16); pq += __shfl_xor(pq, 32);
        float mu = ps * (1.f / 64.f);
        float va = pq * (1.f / 64.f) - mu * mu;
        float is = rsqrtf(va + 1e-5f);
#pragma unroll
        for (int Mt2 = 0; Mt2 < 4; ++Mt2) {
            float4 g4 = *(const float4*)(g2 + 16 * Mt2 + 4 * g);
            float4 b4 = *(const float4*)(b2 + 16 * Mt2 + 4 * g);
            ya[Mt2][0] = (ya[Mt2][0] - mu) * is * g4.x + b4.x;
            ya[Mt2][1] = (ya[Mt2][1] - mu) * is * g4.y + b4.y;
            ya[Mt2][2] = (ya[Mt2][2] - mu) * is * g4.z + b4.z;
            ya[Mt2][3] = (ya[Mt2][3] - mu) * is * g4.w + b4.w;
        }
    }
    // write s_y fp32 [128][64] @16K (swz128 on 256B rows): s_y[q][16Mt2+4g..+3]
#pragma unroll
    for (int Mt2 = 0; Mt2 < 4; ++Mt2) {
        float4 v = { ya[Mt2][0], ya[Mt2][1], ya[Mt2][2], ya[Mt2][3] };
        *(float4*)(smem + 16384 + swz128(q, 4 * Mt2 + g)) = v;
    }
    __syncthreads();   // (7)
    // transpose-read + coalesced store
    {
        int qq = tid >> 2, jb = (tid & 3) * 16;
        float* op = out + (((size_t)b * 128) * 128 + tt) * 64 + (size_t)qq * 8192 + jb;
        float4 v0 = *(const float4*)(smem + 16384 + swz128(qq, (tid & 3) * 4 + 0));
        float4 v1 = *(const float4*)(smem + 16384 + swz128(qq, (tid & 3) * 4 + 1));
        float4 v2 = *(const float4*)(smem + 16384 + swz128(qq, (tid & 3) * 4 + 2));
        float4 v3 = *(const float4*)(smem + 16384 + swz128(qq, (tid & 3) * 4 + 3));
        *(float4*)(op)      = v0;
        *(float4*)(op + 4)  = v1;
        *(float4*)(op + 8)  = v2;
        *(float4*)(op + 12) = v3;
    }
}

extern "C" void kernel_launch(void* const* d_in, const int* in_sizes, int n_in,
                              void* d_out, int out_size, void* d_ws, size_t ws_size,
                              hipStream_t stream) {
    const float* h   = (const float*)d_in[0];
    const float* W   = (const float*)d_in[1];
    const float* wq  = (const float*)d_in[2];
    const float* bq  = (const float*)d_in[3];
    const float* wk  = (const float*)d_in[4];
    const float* bk  = (const float*)d_in[5];
    const float* wv  = (const float*)d_in[6];
    const float* bv  = (const float*)d_in[7];
    const float* wo  = (const float*)d_in[8];
    const float* bo  = (const float*)d_in[9];
    const float* we  = (const float*)d_in[10];
    const float* be  = (const float*)d_in[11];
    const float* g1  = (const float*)d_in[12];
    const float* b1  = (const float*)d_in[13];
    const float* w1  = (const float*)d_in[14];
    const float* bf1 = (const float*)d_in[15];
    const float* w2  = (const float*)d_in[16];
    const float* bf2 = (const float*)d_in[17];
    const float* g2  = (const float*)d_in[18];
    const float* b2  = (const float*)d_in[19];
    float* out = (float*)d_out;

    gal_kernel<<<1024, NTHREADS, 0, stream>>>(
        h, W, wq, bq, wk, bk, wv, bv, wo, bo, we, be,
        g1, b1, w1, bf1, w2, bf2, g2, b2, out);
}

// Round 5
// 74.154 us; speedup vs baseline: 1.4983x; 1.4983x over previous
//
#include <hip/hip_runtime.h>
#include <hip/hip_bf16.h>

#define NTHREADS 512

typedef __attribute__((ext_vector_type(8))) short short8;
typedef __attribute__((ext_vector_type(4))) float f32x4;

#define MFMA(a, b, c) __builtin_amdgcn_mfma_f32_16x16x32_bf16(a, b, c, 0, 0, 0)

__device__ __forceinline__ unsigned short f2u(float x) {
    __hip_bfloat16 b = __float2bfloat16(x);
    return *reinterpret_cast<unsigned short*>(&b);
}
__device__ __forceinline__ float u2f(unsigned short u) {
    unsigned v = ((unsigned)u) << 16;
    return *reinterpret_cast<float*>(&v);
}
__device__ __forceinline__ unsigned pack2(float lo, float hi) {
    return ((unsigned)f2u(hi) << 16) | (unsigned)f2u(lo);
}
// XOR-swizzled byte offsets. [R][64] bf16 rows (128B, 8 chunks of 16B):
__device__ __forceinline__ int swz64(int r, int c8)  { return r * 128 + ((c8 ^ (r & 7)) << 4); }
__device__ __forceinline__ int swz64e(int r, int c)  { return r * 128 + (((c >> 3) ^ (r & 7)) << 4) + ((c & 7) << 1); }
// [R][256B] rows (16 chunks of 16B) — used for bf16 [R][128] and fp32 [R][64]:
__device__ __forceinline__ int swz128(int r, int c8) { return r * 256 + ((c8 ^ (r & 15)) << 4); }
__device__ __forceinline__ int swz128e(int r, int c) { return r * 256 + ((((c >> 3) ^ (r & 15))) << 4) + ((c & 7) << 1); }

__device__ __forceinline__ short8 cvt8(const float* src) {
    float4 f0 = *(const float4*)src;
    float4 f1 = *(const float4*)(src + 4);
    short8 v = { (short)f2u(f0.x), (short)f2u(f0.y), (short)f2u(f0.z), (short)f2u(f0.w),
                 (short)f2u(f1.x), (short)f2u(f1.y), (short)f2u(f1.z), (short)f2u(f1.w) };
    return v;
}

// repack D-layout (row=4g'+jr within K-tile, col=l15) values into a B-fragment
// for the K=32 MFMA chunk kc. p0..p3 are pack2 words of tiles 2kc (p0,p1) and 2kc+1 (p2,p3).
__device__ __forceinline__ short8 repack4(unsigned p0, unsigned p1, unsigned p2, unsigned p3,
                                          int src0, int src1, bool hiMt) {
    unsigned a0 = __shfl((int)p0, src0), a1 = __shfl((int)p1, src0);
    unsigned b0 = __shfl((int)p2, src0), b1 = __shfl((int)p3, src0);
    unsigned a2 = __shfl((int)p0, src1), a3 = __shfl((int)p1, src1);
    unsigned b2 = __shfl((int)p2, src1), b3 = __shfl((int)p3, src1);
    union { unsigned u[4]; short8 s8; } pf;
    pf.u[0] = hiMt ? b0 : a0;
    pf.u[1] = hiMt ? b1 : a1;
    pf.u[2] = hiMt ? b2 : a2;
    pf.u[3] = hiMt ? b3 : a3;
    return pf.s8;
}

__global__ __launch_bounds__(NTHREADS, 4) void gal_kernel(
    const float* __restrict__ h,  const float* __restrict__ W,
    const float* __restrict__ wq, const float* __restrict__ bq,
    const float* __restrict__ wk, const float* __restrict__ bk,
    const float* __restrict__ wv, const float* __restrict__ bv,
    const float* __restrict__ wo, const float* __restrict__ bo,
    const float* __restrict__ we, const float* __restrict__ be,
    const float* __restrict__ g1, const float* __restrict__ b1,
    const float* __restrict__ w1, const float* __restrict__ bf1,
    const float* __restrict__ w2, const float* __restrict__ bff2,
    const float* __restrict__ g2, const float* __restrict__ b2,
    float* __restrict__ out)
{
    // 48 KB LDS, phase-overlaid:
    // A: s_h@0[128][64], wq@16K, wk@24K, wv@32K (each [64][64] 8K)
    // B: s_Q@0[128][64], s_K@16K[128][64], s_VT@32K[64][128]
    // C/D: w2@0[64][128], wo@16K[64][64], w1@24K[128][64]
    // end: s_y fp32 [128][64] @16K..48K (swz128)
    __shared__ __align__(16) unsigned char smem[49152];

    const int gblk = blockIdx.x;
    const int b   = gblk >> 7;
    const int tt  = gblk & 127;
    const int tid = threadIdx.x;
    const int lane = tid & 63;
    const int w   = tid >> 6;      // wave 0..7 owns q-rows 16w..16w+15
    const int l15 = lane & 15;
    const int g   = lane >> 4;     // quarter-group 0..3

    const float* hp = h + (((size_t)b * 128) * 128 + tt) * 64;
    const float* Wb = W + (size_t)b * 128 * 128;

    // ================= Phase A: stage h + QKV weights =================
#pragma unroll
    for (int i = 0; i < 2; ++i) {
        int idx = tid + i * 512;
        int d = idx >> 3, c = idx & 7;
        *(short8*)(smem + swz64(d, c)) = cvt8(hp + (size_t)d * 8192 + c * 8);
    }
    {
        int j = tid >> 3, c = tid & 7;   // 512 threads cover 64x8 exactly
        *(short8*)(smem + 16384 + swz64(j, c)) = cvt8(wq + j * 64 + c * 8);
        *(short8*)(smem + 24576 + swz64(j, c)) = cvt8(wk + j * 64 + c * 8);
        *(short8*)(smem + 32768 + swz64(j, c)) = cvt8(wv + j * 64 + c * 8);
    }
    __syncthreads();   // (1)

    // QKV GEMMs into registers: wave w owns rows 16w..16w+15
    f32x4 aq[4], ak4[4], av4[4];
    {
        short8 ah0 = *(const short8*)(smem + swz64(16 * w + l15, g));
        short8 ah1 = *(const short8*)(smem + swz64(16 * w + l15, g + 4));
        f32x4 z = {0.f, 0.f, 0.f, 0.f};
#pragma unroll
        for (int nt = 0; nt < 4; ++nt) { aq[nt] = z; ak4[nt] = z; av4[nt] = z; }
#pragma unroll
        for (int nt = 0; nt < 4; ++nt) {
#pragma unroll
            for (int kh = 0; kh < 2; ++kh) {
                short8 ah = kh ? ah1 : ah0;
                short8 bwq = *(const short8*)(smem + 16384 + swz64(16 * nt + l15, g + 4 * kh));
                aq[nt] = MFMA(ah, bwq, aq[nt]);
                short8 bwk = *(const short8*)(smem + 24576 + swz64(16 * nt + l15, g + 4 * kh));
                ak4[nt] = MFMA(ah, bwk, ak4[nt]);
                short8 bwv = *(const short8*)(smem + 32768 + swz64(16 * nt + l15, g + 4 * kh));
                av4[nt] = MFMA(ah, bwv, av4[nt]);
            }
        }
    }
    float bqv[4], bkv[4], bvv[4];
#pragma unroll
    for (int nt = 0; nt < 4; ++nt) {
        bqv[nt] = bq[16 * nt + l15]; bkv[nt] = bk[16 * nt + l15]; bvv[nt] = bv[16 * nt + l15];
    }
    __syncthreads();   // (2) all LDS reads done before overwrite
    // write s_Q@0 (row d), s_K@16K (row d), s_VT@32K (row j = H-dim)
#pragma unroll
    for (int nt = 0; nt < 4; ++nt) {
        int j = 16 * nt + l15;
#pragma unroll
        for (int jr = 0; jr < 4; ++jr) {
            int d = 16 * w + 4 * g + jr;
            *(unsigned short*)(smem + swz64e(d, j))          = f2u((aq[nt][jr] + bqv[nt]) * 0.25f);
            *(unsigned short*)(smem + 16384 + swz64e(d, j))  = f2u(ak4[nt][jr] + bkv[nt]);
            *(unsigned short*)(smem + 32768 + swz128e(j, d)) = f2u(av4[nt][jr] + bvv[nt]);
        }
    }
    __syncthreads();   // (3)

    // ================= Phase B: attention (swapped S^T = K*Q^T) =================
    const int q = 16 * w + l15;                 // this lane's q-row
    const int src0 = l15 + ((lane & 16) << 1);  // quarter-shuffle sources
    const int src1 = src0 + 16;
    const bool hiMt = (g >> 1) & 1;

    float osr[4][4];   // O^T[16hd+4g+jr][q] accumulated per head
#pragma unroll
    for (int hd = 0; hd < 4; ++hd) {
        float weh = we[hd];                     // be cancels in softmax
        short8 qf = {0, 0, 0, 0, 0, 0, 0, 0};
        if (g < 2) qf = *(const short8*)(smem + swz64(q, 2 * hd + g));
        f32x4 s[8];
#pragma unroll
        for (int Mt = 0; Mt < 8; ++Mt) {
            float4 w4 = *(const float4*)(Wb + (size_t)q * 128 + 16 * Mt + 4 * g);
            f32x4 c0 = { w4.x * weh, w4.y * weh, w4.z * weh, w4.w * weh };
            short8 kf = {0, 0, 0, 0, 0, 0, 0, 0};
            if (g < 2) kf = *(const short8*)(smem + 16384 + swz64(16 * Mt + l15, 2 * hd + g));
            s[Mt] = MFMA(kf, qf, c0);
        }
        // softmax over kk (row q lives in 4 lanes x 32 regs)
        float mx = s[0][0];
#pragma unroll
        for (int Mt = 0; Mt < 8; ++Mt)
#pragma unroll
            for (int jr = 0; jr < 4; ++jr) mx = fmaxf(mx, s[Mt][jr]);
        mx = fmaxf(mx, __shfl_xor(mx, 16));
        mx = fmaxf(mx, __shfl_xor(mx, 32));
        float tot = 0.f;
#pragma unroll
        for (int Mt = 0; Mt < 8; ++Mt)
#pragma unroll
            for (int jr = 0; jr < 4; ++jr) { s[Mt][jr] = __expf(s[Mt][jr] - mx); tot += s[Mt][jr]; }
        tot += __shfl_xor(tot, 16);
        tot += __shfl_xor(tot, 32);
        float sinv = 1.f / tot;
        unsigned pk[16];
#pragma unroll
        for (int Mt = 0; Mt < 8; ++Mt) {
            pk[2 * Mt]     = pack2(s[Mt][0], s[Mt][1]);
            pk[2 * Mt + 1] = pack2(s[Mt][2], s[Mt][3]);
        }
        // PV: O^T = V^T @ P^T
        f32x4 o = {0.f, 0.f, 0.f, 0.f};
#pragma unroll
        for (int kc = 0; kc < 4; ++kc) {
            short8 pf = repack4(pk[4 * kc], pk[4 * kc + 1], pk[4 * kc + 2], pk[4 * kc + 3],
                                src0, src1, hiMt);
            short8 vf = *(const short8*)(smem + 32768 + swz128(16 * hd + l15, g + 4 * kc));
            o = MFMA(vf, pf, o);
        }
#pragma unroll
        for (int jr = 0; jr < 4; ++jr) osr[hd][jr] = o[jr] * sinv;
    }

    // h^T residual prefetch (global fp32, issued before the barrier)
    float4 hres[4];
#pragma unroll
    for (int Mt2 = 0; Mt2 < 4; ++Mt2)
        hres[Mt2] = *(const float4*)(hp + (size_t)q * 8192 + 16 * Mt2 + 4 * g);
    __syncthreads();   // (4) attention LDS reads done

    // stage w2@0 [64][128], wo@16K [64][64], w1@24K [128][64]
    {
        int j = tid >> 3, c = tid & 7;
        *(short8*)(smem + 16384 + swz64(j, c)) = cvt8(wo + j * 64 + c * 8);
    }
#pragma unroll
    for (int i = 0; i < 2; ++i) {
        int idx = tid + i * 512;
        int m = idx >> 3, c = idx & 7;
        *(short8*)(smem + 24576 + swz64(m, c)) = cvt8(w1 + m * 64 + c * 8);
        int j2 = idx >> 4, c2 = idx & 15;
        *(short8*)(smem + swz128(j2, c2)) = cvt8(w2 + j2 * 128 + c2 * 8);
    }
    __syncthreads();   // (5)

    // ============ Phase C: out-proj (transposed) + residual + LN1, all in regs ============
    f32x4 xt[4];
#pragma unroll
    for (int Mt2 = 0; Mt2 < 4; ++Mt2) {
        float4 bb = *(const float4*)(bo + 16 * Mt2 + 4 * g);
        f32x4 c0 = { bb.x, bb.y, bb.z, bb.w };
        xt[Mt2] = c0;
    }
#pragma unroll
    for (int kc = 0; kc < 2; ++kc) {
        short8 pf = repack4(pack2(osr[2 * kc][0], osr[2 * kc][1]),
                            pack2(osr[2 * kc][2], osr[2 * kc][3]),
                            pack2(osr[2 * kc + 1][0], osr[2 * kc + 1][1]),
                            pack2(osr[2 * kc + 1][2], osr[2 * kc + 1][3]),
                            src0, src1, hiMt);
#pragma unroll
        for (int Mt2 = 0; Mt2 < 4; ++Mt2) {
            short8 awo = *(const short8*)(smem + 16384 + swz64(16 * Mt2 + l15, g + 4 * kc));
            xt[Mt2] = MFMA(awo, pf, xt[Mt2]);
        }
    }
    // residual + LN1 over H-dim (in-lane 16 + shfl 16/32)
    {
        float ps = 0.f, pq = 0.f;
#pragma unroll
        for (int Mt2 = 0; Mt2 < 4; ++Mt2) {
            float4 hv = hres[Mt2];
            xt[Mt2][0] += hv.x; xt[Mt2][1] += hv.y; xt[Mt2][2] += hv.z; xt[Mt2][3] += hv.w;
#pragma unroll
            for (int jr = 0; jr < 4; ++jr) { ps += xt[Mt2][jr]; pq += xt[Mt2][jr] * xt[Mt2][jr]; }
        }
        ps += __shfl_xor(ps, 16); ps += __shfl_xor(ps, 32);
        pq += __shfl_xor(pq, 16); pq += __shfl_xor(pq, 32);
        float mu = ps * (1.f / 64.f);
        float va = pq * (1.f / 64.f) - mu * mu;
        float is = rsqrtf(va + 1e-5f);
#pragma unroll
        for (int Mt2 = 0; Mt2 < 4; ++Mt2) {
            float4 g4 = *(const float4*)(g1 + 16 * Mt2 + 4 * g);
            float4 b4 = *(const float4*)(b1 + 16 * Mt2 + 4 * g);
            xt[Mt2][0] = (xt[Mt2][0] - mu) * is * g4.x + b4.x;
            xt[Mt2][1] = (xt[Mt2][1] - mu) * is * g4.y + b4.y;
            xt[Mt2][2] = (xt[Mt2][2] - mu) * is * g4.z + b4.z;
            xt[Mt2][3] = (xt[Mt2][3] - mu) * is * g4.w + b4.w;
        }
    }

    // ============ Phase D: FFN (transposed) + residual + LN2 ============
    f32x4 tacc[8];
#pragma unroll
    for (int Mt = 0; Mt < 8; ++Mt) {
        float4 bb = *(const float4*)(bf1 + 16 * Mt + 4 * g);
        f32x4 c0 = { bb.x, bb.y, bb.z, bb.w };
        tacc[Mt] = c0;
    }
#pragma unroll
    for (int kc = 0; kc < 2; ++kc) {
        short8 pf = repack4(pack2(xt[2 * kc][0], xt[2 * kc][1]),
                            pack2(xt[2 * kc][2], xt[2 * kc][3]),
                            pack2(xt[2 * kc + 1][0], xt[2 * kc + 1][1]),
                            pack2(xt[2 * kc + 1][2], xt[2 * kc + 1][3]),
                            src0, src1, hiMt);
#pragma unroll
        for (int Mt = 0; Mt < 8; ++Mt) {
            short8 aw1 = *(const short8*)(smem + 24576 + swz64(16 * Mt + l15, g + 4 * kc));
            tacc[Mt] = MFMA(aw1, pf, tacc[Mt]);
        }
    }
    unsigned pkt[16];
#pragma unroll
    for (int Mt = 0; Mt < 8; ++Mt) {
        float v0 = tacc[Mt][0], v1 = tacc[Mt][1], v2 = tacc[Mt][2], v3 = tacc[Mt][3];
        v0 = 0.5f * v0 * (1.f + erff(v0 * 0.70710678118f));
        v1 = 0.5f * v1 * (1.f + erff(v1 * 0.70710678118f));
        v2 = 0.5f * v2 * (1.f + erff(v2 * 0.70710678118f));
        v3 = 0.5f * v3 * (1.f + erff(v3 * 0.70710678118f));
        pkt[2 * Mt]     = pack2(v0, v1);
        pkt[2 * Mt + 1] = pack2(v2, v3);
    }
    __syncthreads();   // (6) w1/wo reads done; s_y may overwrite them after this

    f32x4 ya[4];
#pragma unroll
    for (int Mt2 = 0; Mt2 < 4; ++Mt2) {
        float4 bb = *(const float4*)(bff2 + 16 * Mt2 + 4 * g);
        f32x4 c0 = { bb.x, bb.y, bb.z, bb.w };
        ya[Mt2] = c0;
    }
#pragma unroll
    for (int kc = 0; kc < 4; ++kc) {
        short8 pf = repack4(pkt[4 * kc], pkt[4 * kc + 1], pkt[4 * kc + 2], pkt[4 * kc + 3],
                            src0, src1, hiMt);
#pragma unroll
        for (int Mt2 = 0; Mt2 < 4; ++Mt2) {
            short8 aw2 = *(const short8*)(smem + swz128(16 * Mt2 + l15, g + 4 * kc));
            ya[Mt2] = MFMA(aw2, pf, ya[Mt2]);
        }
    }
    // residual from xt (in regs) + LN2
    {
        float ps = 0.f, pq = 0.f;
#pragma unroll
        for (int Mt2 = 0; Mt2 < 4; ++Mt2) {
#pragma unroll
            for (int jr = 0; jr < 4; ++jr) {
                ya[Mt2][jr] += xt[Mt2][jr];
                ps += ya[Mt2][jr]; pq += ya[Mt2][jr] * ya[Mt2][jr];
            }
        }
        ps += __shfl_xor(ps, 16); ps += __shfl_xor(ps, 32);
        pq += __shfl_xor(pq, 16); pq += __shfl_xor(pq, 32);
        float mu = ps * (1.f / 64.f);
        float va = pq * (1.f / 64.f) - mu * mu;
        float is = rsqrtf(va + 1e-5f);
#pragma unroll
        for (int Mt2 = 0; Mt2 < 4; ++Mt2) {
            float4 g4 = *(const float4*)(g2 + 16 * Mt2 + 4 * g);
            float4 b4 = *(const float4*)(b2 + 16 * Mt2 + 4 * g);
            ya[Mt2][0] = (ya[Mt2][0] - mu) * is * g4.x + b4.x;
            ya[Mt2][1] = (ya[Mt2][1] - mu) * is * g4.y + b4.y;
            ya[Mt2][2] = (ya[Mt2][2] - mu) * is * g4.z + b4.z;
            ya[Mt2][3] = (ya[Mt2][3] - mu) * is * g4.w + b4.w;
        }
    }
    // write s_y fp32 [128][64] @16K (swz128 on 256B rows): s_y[q][16Mt2+4g..+3]
#pragma unroll
    for (int Mt2 = 0; Mt2 < 4; ++Mt2) {
        float4 v = { ya[Mt2][0], ya[Mt2][1], ya[Mt2][2], ya[Mt2][3] };
        *(float4*)(smem + 16384 + swz128(q, 4 * Mt2 + g)) = v;
    }
    __syncthreads();   // (7)
    // transpose-read + coalesced store
    {
        int qq = tid >> 2, jb = (tid & 3) * 16;
        float* op = out + (((size_t)b * 128) * 128 + tt) * 64 + (size_t)qq * 8192 + jb;
        float4 v0 = *(const float4*)(smem + 16384 + swz128(qq, (tid & 3) * 4 + 0));
        float4 v1 = *(const float4*)(smem + 16384 + swz128(qq, (tid & 3) * 4 + 1));
        float4 v2 = *(const float4*)(smem + 16384 + swz128(qq, (tid & 3) * 4 + 2));
        float4 v3 = *(const float4*)(smem + 16384 + swz128(qq, (tid & 3) * 4 + 3));
        *(float4*)(op)      = v0;
        *(float4*)(op + 4)  = v1;
        *(float4*)(op + 8)  = v2;
        *(float4*)(op + 12) = v3;
    }
}

extern "C" void kernel_launch(void* const* d_in, const int* in_sizes, int n_in,
                              void* d_out, int out_size, void* d_ws, size_t ws_size,
                              hipStream_t stream) {
    const float* h   = (const float*)d_in[0];
    const float* W   = (const float*)d_in[1];
    const float* wq  = (const float*)d_in[2];
    const float* bq  = (const float*)d_in[3];
    const float* wk  = (const float*)d_in[4];
    const float* bk  = (const float*)d_in[5];
    const float* wv  = (const float*)d_in[6];
    const float* bv  = (const float*)d_in[7];
    const float* wo  = (const float*)d_in[8];
    const float* bo  = (const float*)d_in[9];
    const float* we  = (const float*)d_in[10];
    const float* be  = (const float*)d_in[11];
    const float* g1  = (const float*)d_in[12];
    const float* b1  = (const float*)d_in[13];
    const float* w1  = (const float*)d_in[14];
    const float* bf1 = (const float*)d_in[15];
    const float* w2  = (const float*)d_in[16];
    const float* bf2 = (const float*)d_in[17];
    const float* g2  = (const float*)d_in[18];
    const float* b2  = (const float*)d_in[19];
    float* out = (float*)d_out;

    gal_kernel<<<1024, NTHREADS, 0, stream>>>(
        h, W, wq, bq, wk, bk, wv, bv, wo, bo, we, be,
        g1, b1, w1, bf1, w2, bf2, g2, b2, out);
}

// Round 12
// 73.903 us; speedup vs baseline: 1.5035x; 1.0034x over previous
//
#include <hip/hip_runtime.h>
#include <hip/hip_bf16.h>

#define NTHREADS 512

typedef __attribute__((ext_vector_type(8))) short short8;
typedef __attribute__((ext_vector_type(4))) float f32x4;

#define MFMA(a, b, c) __builtin_amdgcn_mfma_f32_16x16x32_bf16(a, b, c, 0, 0, 0)

__device__ __forceinline__ unsigned short f2u(float x) {
    __hip_bfloat16 b = __float2bfloat16(x);
    return *reinterpret_cast<unsigned short*>(&b);
}
__device__ __forceinline__ float u2f(unsigned short u) {
    unsigned v = ((unsigned)u) << 16;
    return *reinterpret_cast<float*>(&v);
}
__device__ __forceinline__ unsigned pack2(float lo, float hi) {
    return ((unsigned)f2u(hi) << 16) | (unsigned)f2u(lo);
}
// XOR-swizzled byte offsets. [R][64] bf16 rows (128B, 8 chunks of 16B):
__device__ __forceinline__ int swz64(int r, int c8)  { return r * 128 + ((c8 ^ (r & 7)) << 4); }
__device__ __forceinline__ int swz64e(int r, int c)  { return r * 128 + (((c >> 3) ^ (r & 7)) << 4) + ((c & 7) << 1); }
// [R][256B] rows (16 chunks of 16B) — used for bf16 [R][128] and fp32 [R][64]:
__device__ __forceinline__ int swz128(int r, int c8) { return r * 256 + ((c8 ^ (r & 15)) << 4); }
__device__ __forceinline__ int swz128e(int r, int c) { return r * 256 + ((((c >> 3) ^ (r & 15))) << 4) + ((c & 7) << 1); }

__device__ __forceinline__ short8 cvt8(const float* src) {
    float4 f0 = *(const float4*)src;
    float4 f1 = *(const float4*)(src + 4);
    short8 v = { (short)f2u(f0.x), (short)f2u(f0.y), (short)f2u(f0.z), (short)f2u(f0.w),
                 (short)f2u(f1.x), (short)f2u(f1.y), (short)f2u(f1.z), (short)f2u(f1.w) };
    return v;
}

// repack D-layout (row=4g'+jr within K-tile, col=l15) values into a B-fragment
__device__ __forceinline__ short8 repack4(unsigned p0, unsigned p1, unsigned p2, unsigned p3,
                                          int src0, int src1, bool hiMt) {
    unsigned a0 = __shfl((int)p0, src0), a1 = __shfl((int)p1, src0);
    unsigned b0 = __shfl((int)p2, src0), b1 = __shfl((int)p3, src0);
    unsigned a2 = __shfl((int)p0, src1), a3 = __shfl((int)p1, src1);
    unsigned b2 = __shfl((int)p2, src1), b3 = __shfl((int)p3, src1);
    union { unsigned u[4]; short8 s8; } pf;
    pf.u[0] = hiMt ? b0 : a0;
    pf.u[1] = hiMt ? b1 : a1;
    pf.u[2] = hiMt ? b2 : a2;
    pf.u[3] = hiMt ? b3 : a3;
    return pf.s8;
}

__global__ __launch_bounds__(NTHREADS, 4) void gal_kernel(
    const float* __restrict__ h,  const float* __restrict__ W,
    const float* __restrict__ wq, const float* __restrict__ bq,
    const float* __restrict__ wk, const float* __restrict__ bk,
    const float* __restrict__ wv, const float* __restrict__ bv,
    const float* __restrict__ wo, const float* __restrict__ bo,
    const float* __restrict__ we, const float* __restrict__ be,
    const float* __restrict__ g1, const float* __restrict__ b1,
    const float* __restrict__ w1, const float* __restrict__ bf1,
    const float* __restrict__ w2, const float* __restrict__ bff2,
    const float* __restrict__ g2, const float* __restrict__ b2,
    float* __restrict__ out)
{
    // 48 KB LDS, phase-overlaid:
    // A: s_h@0[128][64], wq@16K, wk@24K, wv@32K (each [64][64] 8K)
    // B: s_Q@0[128][64], s_K@16K[128][64], s_VT@32K[64][128]
    // C/D: w2@0[64][128], wo@16K[64][64], w1@24K[128][64]
    // end: s_y fp32 [128][64] @16K..48K (swz128)
    __shared__ __align__(16) unsigned char smem[49152];

    const int gblk = blockIdx.x;
    const int b   = gblk >> 7;
    const int tt  = gblk & 127;
    const int tid = threadIdx.x;
    const int lane = tid & 63;
    const int w   = tid >> 6;      // wave 0..7 owns q-rows 16w..16w+15
    const int l15 = lane & 15;
    const int g   = lane >> 4;     // quarter-group 0..3

    const float* hp = h + (((size_t)b * 128) * 128 + tt) * 64;
    const float* Wb = W + (size_t)b * 128 * 128;

    // ================= Phase A: stage h + QKV weights =================
#pragma unroll
    for (int i = 0; i < 2; ++i) {
        int idx = tid + i * 512;
        int d = idx >> 3, c = idx & 7;
        *(short8*)(smem + swz64(d, c)) = cvt8(hp + (size_t)d * 8192 + c * 8);
    }
    {
        int j = tid >> 3, c = tid & 7;   // 512 threads cover 64x8 exactly
        *(short8*)(smem + 16384 + swz64(j, c)) = cvt8(wq + j * 64 + c * 8);
        *(short8*)(smem + 24576 + swz64(j, c)) = cvt8(wk + j * 64 + c * 8);
        *(short8*)(smem + 32768 + swz64(j, c)) = cvt8(wv + j * 64 + c * 8);
    }
    __syncthreads();   // (1)

    // QKV GEMMs into registers: wave w owns rows 16w..16w+15
    f32x4 aq[4], ak4[4], av4[4];
    {
        short8 ah0 = *(const short8*)(smem + swz64(16 * w + l15, g));
        short8 ah1 = *(const short8*)(smem + swz64(16 * w + l15, g + 4));
        f32x4 z = {0.f, 0.f, 0.f, 0.f};
#pragma unroll
        for (int nt = 0; nt < 4; ++nt) { aq[nt] = z; ak4[nt] = z; av4[nt] = z; }
#pragma unroll
        for (int nt = 0; nt < 4; ++nt) {
#pragma unroll
            for (int kh = 0; kh < 2; ++kh) {
                short8 ah = kh ? ah1 : ah0;
                short8 bwq = *(const short8*)(smem + 16384 + swz64(16 * nt + l15, g + 4 * kh));
                aq[nt] = MFMA(ah, bwq, aq[nt]);
                short8 bwk = *(const short8*)(smem + 24576 + swz64(16 * nt + l15, g + 4 * kh));
                ak4[nt] = MFMA(ah, bwk, ak4[nt]);
                short8 bwv = *(const short8*)(smem + 32768 + swz64(16 * nt + l15, g + 4 * kh));
                av4[nt] = MFMA(ah, bwv, av4[nt]);
            }
        }
    }
    float bqv[4], bkv[4], bvv[4];
#pragma unroll
    for (int nt = 0; nt < 4; ++nt) {
        bqv[nt] = bq[16 * nt + l15]; bkv[nt] = bk[16 * nt + l15]; bvv[nt] = bv[16 * nt + l15];
    }
    __syncthreads();   // (2) all LDS reads done before overwrite
    // write s_Q@0 (row d), s_K@16K (row d), s_VT@32K (row j = H-dim)
#pragma unroll
    for (int nt = 0; nt < 4; ++nt) {
        int j = 16 * nt + l15;
#pragma unroll
        for (int jr = 0; jr < 4; ++jr) {
            int d = 16 * w + 4 * g + jr;
            *(unsigned short*)(smem + swz64e(d, j))          = f2u((aq[nt][jr] + bqv[nt]) * 0.25f);
            *(unsigned short*)(smem + 16384 + swz64e(d, j))  = f2u(ak4[nt][jr] + bkv[nt]);
            *(unsigned short*)(smem + 32768 + swz128e(j, d)) = f2u(av4[nt][jr] + bvv[nt]);
        }
    }
    __syncthreads();   // (3)

    // ================= Phase B: attention (swapped S^T = K*Q^T) =================
    const int q = 16 * w + l15;                 // this lane's q-row
    const int src0 = l15 + ((lane & 16) << 1);  // quarter-shuffle sources
    const int src1 = src0 + 16;
    const bool hiMt = (g >> 1) & 1;

    float osr[4][4];   // O^T[16hd+4g+jr][q] accumulated per head
#pragma unroll
    for (int hd = 0; hd < 4; ++hd) {
        float weh = we[hd];                     // be cancels in softmax
        short8 qf = {0, 0, 0, 0, 0, 0, 0, 0};
        if (g < 2) qf = *(const short8*)(smem + swz64(q, 2 * hd + g));
        f32x4 s[8];
#pragma unroll
        for (int Mt = 0; Mt < 8; ++Mt) {
            float4 w4 = *(const float4*)(Wb + (size_t)q * 128 + 16 * Mt + 4 * g);
            f32x4 c0 = { w4.x * weh, w4.y * weh, w4.z * weh, w4.w * weh };
            short8 kf = {0, 0, 0, 0, 0, 0, 0, 0};
            if (g < 2) kf = *(const short8*)(smem + 16384 + swz64(16 * Mt + l15, 2 * hd + g));
            s[Mt] = MFMA(kf, qf, c0);
        }
        float mx = s[0][0];
#pragma unroll
        for (int Mt = 0; Mt < 8; ++Mt)
#pragma unroll
            for (int jr = 0; jr < 4; ++jr) mx = fmaxf(mx, s[Mt][jr]);
        mx = fmaxf(mx, __shfl_xor(mx, 16));
        mx = fmaxf(mx, __shfl_xor(mx, 32));
        float tot = 0.f;
#pragma unroll
        for (int Mt = 0; Mt < 8; ++Mt)
#pragma unroll
            for (int jr = 0; jr < 4; ++jr) { s[Mt][jr] = __expf(s[Mt][jr] - mx); tot += s[Mt][jr]; }
        tot += __shfl_xor(tot, 16);
        tot += __shfl_xor(tot, 32);
        float sinv = 1.f / tot;
        unsigned pk[16];
#pragma unroll
        for (int Mt = 0; Mt < 8; ++Mt) {
            pk[2 * Mt]     = pack2(s[Mt][0], s[Mt][1]);
            pk[2 * Mt + 1] = pack2(s[Mt][2], s[Mt][3]);
        }
        f32x4 o = {0.f, 0.f, 0.f, 0.f};
#pragma unroll
        for (int kc = 0; kc < 4; ++kc) {
            short8 pf = repack4(pk[4 * kc], pk[4 * kc + 1], pk[4 * kc + 2], pk[4 * kc + 3],
                                src0, src1, hiMt);
            short8 vf = *(const short8*)(smem + 32768 + swz128(16 * hd + l15, g + 4 * kc));
            o = MFMA(vf, pf, o);
        }
#pragma unroll
        for (int jr = 0; jr < 4; ++jr) osr[hd][jr] = o[jr] * sinv;
    }

    // h^T residual prefetch (global fp32, issued before the barrier)
    float4 hres[4];
#pragma unroll
    for (int Mt2 = 0; Mt2 < 4; ++Mt2)
        hres[Mt2] = *(const float4*)(hp + (size_t)q * 8192 + 16 * Mt2 + 4 * g);
    __syncthreads();   // (4) attention LDS reads done

    // stage w2@0 [64][128], wo@16K [64][64], w1@24K [128][64]
    {
        int j = tid >> 3, c = tid & 7;
        *(short8*)(smem + 16384 + swz64(j, c)) = cvt8(wo + j * 64 + c * 8);
    }
#pragma unroll
    for (int i = 0; i < 2; ++i) {
        int idx = tid + i * 512;
        int m = idx >> 3, c = idx & 7;
        *(short8*)(smem + 24576 + swz64(m, c)) = cvt8(w1 + m * 64 + c * 8);
        int j2 = idx >> 4, c2 = idx & 15;
        *(short8*)(smem + swz128(j2, c2)) = cvt8(w2 + j2 * 128 + c2 * 8);
    }
    __syncthreads();   // (5)

    // ============ Phase C: out-proj (transposed) + residual + LN1, all in regs ============
    f32x4 xt[4];
#pragma unroll
    for (int Mt2 = 0; Mt2 < 4; ++Mt2) {
        float4 bb = *(const float4*)(bo + 16 * Mt2 + 4 * g);
        f32x4 c0 = { bb.x, bb.y, bb.z, bb.w };
        xt[Mt2] = c0;
    }
#pragma unroll
    for (int kc = 0; kc < 2; ++kc) {
        short8 pf = repack4(pack2(osr[2 * kc][0], osr[2 * kc][1]),
                            pack2(osr[2 * kc][2], osr[2 * kc][3]),
                            pack2(osr[2 * kc + 1][0], osr[2 * kc + 1][1]),
                            pack2(osr[2 * kc + 1][2], osr[2 * kc + 1][3]),
                            src0, src1, hiMt);
#pragma unroll
        for (int Mt2 = 0; Mt2 < 4; ++Mt2) {
            short8 awo = *(const short8*)(smem + 16384 + swz64(16 * Mt2 + l15, g + 4 * kc));
            xt[Mt2] = MFMA(awo, pf, xt[Mt2]);
        }
    }
    // residual + LN1 over H-dim (in-lane 16 + shfl 16/32)
    {
        float ps = 0.f, pq = 0.f;
#pragma unroll
        for (int Mt2 = 0; Mt2 < 4; ++Mt2) {
            float4 hv = hres[Mt2];
            xt[Mt2][0] += hv.x; xt[Mt2][1] += hv.y; xt[Mt2][2] += hv.z; xt[Mt2][3] += hv.w;
#pragma unroll
            for (int jr = 0; jr < 4; ++jr) { ps += xt[Mt2][jr]; pq += xt[Mt2][jr] * xt[Mt2][jr]; }
        }
        ps += __shfl_xor(ps, 16); ps += __shfl_xor(ps, 32);
        pq += __shfl_xor(pq, 16); pq += __shfl_xor(pq, 32);
        float mu = ps * (1.f / 64.f);
        float va = pq * (1.f / 64.f) - mu * mu;
        float is = rsqrtf(va + 1e-5f);
#pragma unroll
        for (int Mt2 = 0; Mt2 < 4; ++Mt2) {
            float4 g4 = *(const float4*)(g1 + 16 * Mt2 + 4 * g);
            float4 b4 = *(const float4*)(b1 + 16 * Mt2 + 4 * g);
            xt[Mt2][0] = (xt[Mt2][0] - mu) * is * g4.x + b4.x;
            xt[Mt2][1] = (xt[Mt2][1] - mu) * is * g4.y + b4.y;
            xt[Mt2][2] = (xt[Mt2][2] - mu) * is * g4.z + b4.z;
            xt[Mt2][3] = (xt[Mt2][3] - mu) * is * g4.w + b4.w;
        }
    }

    // ============ Phase D: FFN (transposed) + residual + LN2 ============
    f32x4 tacc[8];
#pragma unroll
    for (int Mt = 0; Mt < 8; ++Mt) {
        float4 bb = *(const float4*)(bf1 + 16 * Mt + 4 * g);
        f32x4 c0 = { bb.x, bb.y, bb.z, bb.w };
        tacc[Mt] = c0;
    }
#pragma unroll
    for (int kc = 0; kc < 2; ++kc) {
        short8 pf = repack4(pack2(xt[2 * kc][0], xt[2 * kc][1]),
                            pack2(xt[2 * kc][2], xt[2 * kc][3]),
                            pack2(xt[2 * kc + 1][0], xt[2 * kc + 1][1]),
                            pack2(xt[2 * kc + 1][2], xt[2 * kc + 1][3]),
                            src0, src1, hiMt);
#pragma unroll
        for (int Mt = 0; Mt < 8; ++Mt) {
            short8 aw1 = *(const short8*)(smem + 24576 + swz64(16 * Mt + l15, g + 4 * kc));
            tacc[Mt] = MFMA(aw1, pf, tacc[Mt]);
        }
    }
    unsigned pkt[16];
#pragma unroll
    for (int Mt = 0; Mt < 8; ++Mt) {
        float v0 = tacc[Mt][0], v1 = tacc[Mt][1], v2 = tacc[Mt][2], v3 = tacc[Mt][3];
        v0 = 0.5f * v0 * (1.f + erff(v0 * 0.70710678118f));
        v1 = 0.5f * v1 * (1.f + erff(v1 * 0.70710678118f));
        v2 = 0.5f * v2 * (1.f + erff(v2 * 0.70710678118f));
        v3 = 0.5f * v3 * (1.f + erff(v3 * 0.70710678118f));
        pkt[2 * Mt]     = pack2(v0, v1);
        pkt[2 * Mt + 1] = pack2(v2, v3);
    }
    __syncthreads();   // (6) w1/wo reads done; s_y may overwrite them after this

    f32x4 ya[4];
#pragma unroll
    for (int Mt2 = 0; Mt2 < 4; ++Mt2) {
        float4 bb = *(const float4*)(bff2 + 16 * Mt2 + 4 * g);
        f32x4 c0 = { bb.x, bb.y, bb.z, bb.w };
        ya[Mt2] = c0;
    }
#pragma unroll
    for (int kc = 0; kc < 4; ++kc) {
        short8 pf = repack4(pkt[4 * kc], pkt[4 * kc + 1], pkt[4 * kc + 2], pkt[4 * kc + 3],
                            src0, src1, hiMt);
#pragma unroll
        for (int Mt2 = 0; Mt2 < 4; ++Mt2) {
            short8 aw2 = *(const short8*)(smem + swz128(16 * Mt2 + l15, g + 4 * kc));
            ya[Mt2] = MFMA(aw2, pf, ya[Mt2]);
        }
    }
    // residual from xt (in regs) + LN2
    {
        float ps = 0.f, pq = 0.f;
#pragma unroll
        for (int Mt2 = 0; Mt2 < 4; ++Mt2) {
#pragma unroll
            for (int jr = 0; jr < 4; ++jr) {
                ya[Mt2][jr] += xt[Mt2][jr];
                ps += ya[Mt2][jr]; pq += ya[Mt2][jr] * ya[Mt2][jr];
            }
        }
        ps += __shfl_xor(ps, 16); ps += __shfl_xor(ps, 32);
        pq += __shfl_xor(pq, 16); pq += __shfl_xor(pq, 32);
        float mu = ps * (1.f / 64.f);
        float va = pq * (1.f / 64.f) - mu * mu;
        float is = rsqrtf(va + 1e-5f);
#pragma unroll
        for (int Mt2 = 0; Mt2 < 4; ++Mt2) {
            float4 g4 = *(const float4*)(g2 + 16 * Mt2 + 4 * g);
            float4 b4 = *(const float4*)(b2 + 16 * Mt2 + 4 * g);
            ya[Mt2][0] = (ya[Mt2][0] - mu) * is * g4.x + b4.x;
            ya[Mt2][1] = (ya[Mt2][1] - mu) * is * g4.y + b4.y;
            ya[Mt2][2] = (ya[Mt2][2] - mu) * is * g4.z + b4.z;
            ya[Mt2][3] = (ya[Mt2][3] - mu) * is * g4.w + b4.w;
        }
    }
    // write s_y fp32 [128][64] @16K (swz128 on 256B rows): s_y[q][16Mt2+4g..+3]
#pragma unroll
    for (int Mt2 = 0; Mt2 < 4; ++Mt2) {
        float4 v = { ya[Mt2][0], ya[Mt2][1], ya[Mt2][2], ya[Mt2][3] };
        *(float4*)(smem + 16384 + swz128(q, 4 * Mt2 + g)) = v;
    }
    __syncthreads();   // (7)
    // transpose-read + coalesced store
    {
        int qq = tid >> 2, jb = (tid & 3) * 16;
        float* op = out + (((size_t)b * 128) * 128 + tt) * 64 + (size_t)qq * 8192 + jb;
        float4 v0 = *(const float4*)(smem + 16384 + swz128(qq, (tid & 3) * 4 + 0));
        float4 v1 = *(const float4*)(smem + 16384 + swz128(qq, (tid & 3) * 4 + 1));
        float4 v2 = *(const float4*)(smem + 16384 + swz128(qq, (tid & 3) * 4 + 2));
        float4 v3 = *(const float4*)(smem + 16384 + swz128(qq, (tid & 3) * 4 + 3));
        *(float4*)(op)      = v0;
        *(float4*)(op + 4)  = v1;
        *(float4*)(op + 8)  = v2;
        *(float4*)(op + 12) = v3;
    }
}

extern "C" void kernel_launch(void* const* d_in, const int* in_sizes, int n_in,
                              void* d_out, int out_size, void* d_ws, size_t ws_size,
                              hipStream_t stream) {
    const float* h   = (const float*)d_in[0];
    const float* W   = (const float*)d_in[1];
    const float* wq  = (const float*)d_in[2];
    const float* bq  = (const float*)d_in[3];
    const float* wk  = (const float*)d_in[4];
    const float* bk  = (const float*)d_in[5];
    const float* wv  = (const float*)d_in[6];
    const float* bv  = (const float*)d_in[7];
    const float* wo  = (const float*)d_in[8];
    const float* bo  = (const float*)d_in[9];
    const float* we  = (const float*)d_in[10];
    const float* be  = (const float*)d_in[11];
    const float* g1  = (const float*)d_in[12];
    const float* b1  = (const float*)d_in[13];
    const float* w1  = (const float*)d_in[14];
    const float* bf1 = (const float*)d_in[15];
    const float* w2  = (const float*)d_in[16];
    const float* bf2 = (const float*)d_in[17];
    const float* g2  = (const float*)d_in[18];
    const float* b2  = (const float*)d_in[19];
    float* out = (float*)d_out;

    gal_kernel<<<1024, NTHREADS, 0, stream>>>(
        h, W, wq, bq, wk, bk, wv, bv, wo, bo, we, be,
        g1, b1, w1, bf1, w2, bf2, g2, b2, out);
}